// Round 6
// baseline (382.974 us; speedup 1.0000x reference)
//
#include <hip/hip_runtime.h>

// B=8, N=256, D=128
// out[b,i,d] = sum_e T[b,i,e]*W[e,d] + bias[d]
//   T[b,i,e]  = sum_j adj[b,i,j] * (hidden[b,j,e] + dep[b,j,i,e])
//
// Wide-slab single kernel: block = (b, 8 consecutive i). 256 blocks = 1/CU.
// Per j the block reads dep[b,j,i0:i0+8,:] = 4 KB CONTIGUOUS and walks j
// sequentially -> long DRAM bursts (v1/v5 read 512 B per 128 KB stride per
// block => row-buffer thrash at ~2.9 TB/s). Each thread owns one
// (i_local, e-chunk) for ALL j: complete T in registers, no partials, no
// workspace, no second dispatch, no barrier in the hot loop. 8-deep unroll
// gives 8 NT dep loads in flight/thread (4 waves/CU x 8 KB >> latency-BW
// product). Epilogue: T -> LDS, 128x128 W matvec (L2-hot), + bias.

constexpr int Bc = 8;
constexpr int Nc = 256;
constexpr int Dc = 128;
constexpr int IT = 8;            // i per block
constexpr int NIQ = Nc / IT;     // 32

typedef float floatx4 __attribute__((ext_vector_type(4)));

__global__ void depgcn_kernel(
    const float* __restrict__ hidden,  // [B,N,D]
    const float* __restrict__ adj,     // [B,N,N]
    const float* __restrict__ dep,     // [B,N,N,D]
    const float* __restrict__ W,       // [D,D]
    const float* __restrict__ bias,    // [D]
    float* __restrict__ out)           // [B,N,D]
{
    const int blk = blockIdx.x;       // 0..255
    const int iq  = blk & (NIQ - 1);
    const int b   = blk >> 5;
    const int i0  = iq * IT;
    const int t   = threadIdx.x;      // 0..255
    const int iL  = t >> 5;           // 0..7  (owned i row)
    const int c   = t & 31;           // e-chunk: e = 4c..4c+3

    __shared__ float sAdj[IT][Nc];    // 8 KB  adj rows for this i-tile
    __shared__ float sT[IT][Dc];      // 4 KB  finished T values

    // stage adj[b, i0..i0+8, :]  (8 floats per thread)
    {
        const int r  = t >> 5;               // row 0..7
        const int cc = (t & 31) * 8;         // col 0..248
        const float* ap = adj + ((size_t)b * Nc + i0 + r) * Nc + cc;
        *(floatx4*)&sAdj[r][cc]     = *(const floatx4*)ap;
        *(floatx4*)&sAdj[r][cc + 4] = *(const floatx4*)(ap + 4);
    }
    __syncthreads();

    // hot loop: acc(iL, e-chunk) over all j
    const float* depP = dep + (((size_t)b * Nc) * Nc + i0 + iL) * Dc + (size_t)c * 4;
    const float* hidP = hidden + ((size_t)b * Nc) * Dc + (size_t)c * 4;

    floatx4 acc = {0.f, 0.f, 0.f, 0.f};

    for (int j0 = 0; j0 < Nc; j0 += 8) {
        floatx4 d[8], h[8];
        #pragma unroll
        for (int k = 0; k < 8; ++k)
            d[k] = __builtin_nontemporal_load(
                (const floatx4*)(depP + (size_t)(j0 + k) * Nc * Dc));
        #pragma unroll
        for (int k = 0; k < 8; ++k)
            h[k] = *(const floatx4*)(hidP + (size_t)(j0 + k) * Dc);
        #pragma unroll
        for (int k = 0; k < 8; ++k) {
            const float a = sAdj[iL][j0 + k];
            acc += a * (d[k] + h[k]);
        }
    }

    *(floatx4*)&sT[iL][c * 4] = acc;
    __syncthreads();

    // epilogue: out[b, i0+iL, d] = sum_e sT[iL][e]*W[e,d] + bias[d]
    // thread (iL, c) computes d = c, c+32, c+64, c+96
    {
        float s0 = bias[c], s1 = bias[c + 32], s2 = bias[c + 64], s3 = bias[c + 96];
        #pragma unroll 8
        for (int e = 0; e < Dc; ++e) {
            const float te = sT[iL][e];
            const float* wr = W + (size_t)e * Dc;
            s0 = fmaf(te, wr[c],      s0);
            s1 = fmaf(te, wr[c + 32], s1);
            s2 = fmaf(te, wr[c + 64], s2);
            s3 = fmaf(te, wr[c + 96], s3);
        }
        float* op = out + ((size_t)b * Nc + i0 + iL) * Dc;
        op[c]      = s0;
        op[c + 32] = s1;
        op[c + 64] = s2;
        op[c + 96] = s3;
    }
}

extern "C" void kernel_launch(void* const* d_in, const int* in_sizes, int n_in,
                              void* d_out, int out_size, void* d_ws, size_t ws_size,
                              hipStream_t stream) {
    const float* hidden = (const float*)d_in[0];
    const float* adj    = (const float*)d_in[1];
    const float* dep    = (const float*)d_in[2];
    const float* W      = (const float*)d_in[3];
    const float* bias   = (const float*)d_in[4];
    float* out          = (float*)d_out;

    depgcn_kernel<<<dim3(Bc * NIQ), dim3(256), 0, stream>>>(hidden, adj, dep, W, bias, out);
}